// Round 2
// baseline (1085.028 us; speedup 1.0000x reference)
//
#include <hip/hip_runtime.h>
#include <cfloat>

// ClDiceLoss (B=2, C=1, 192^3) fp32 — register-streaming soft-skeletonize.
//
// Round-9: round-8 removed LDS and became LATENCY-bound (occ 26% = 3 waves/
// SIMD, VALU 41%, HBM 38% — nothing saturated). This round:
//   (a) CZ 48->24: grid 768->1536 blocks = 6 blocks/CU = 6 waves/SIMD
//       (launch_bounds(256,6); VGPR cap 85, used ~60). 2x latency hiding
//       for +8% fetch overlap.
//   (b) separable 3x3 in-plane max: row-max in-register, THEN 2 shfls
//       (8 bpermutes/step instead of 12).
//   (c) dwordx3 loads/stores: 5 VMEM instr/step instead of 15 (lane spans
//       12B; wave spans contiguous 768B -> fully coalesced).
// Decomposition unchanged: W = 192 = 64 lanes x 3 cols -> one wave spans
// full x; wave owns y-row gy; streams z with a 4-deep register plane ring
// (rows gy-2..gy+2 per plane; halo rows re-read from global = L2 hits).
// Boundaries: x edge == wave edge -> cndmask pads; y edge -> -FLT_MAX row
// mask on M; z edge -> zlo/zhi guards; clamped dup loads are min-neutral.
// No __shared__, no __syncthreads in skel_iter.

constexpr int D = 192, H = 192, W = 192, B = 2;
constexpr int HW = H * W;
constexpr int VOL = D * HW;
constexpr int CZ = 24;              // z-chunk (multiple of 4; divides D)
constexpr int NCH = D / CZ;         // 8 chunks
constexpr int WPB = 4;              // waves (y-strips) per block
constexpr int NGY = H / WPB;        // 48
constexpr int STEPS = CZ + 4;       // 28 pipeline steps (multiple of 4)
constexpr int NPART = B * NCH * H;  // 3072 per chain

struct F3 { float x, y, z; };       // 12B, align 4 -> global_load_dwordx3

__device__ __forceinline__ float max3(float a, float b, float c) {
  return fmaxf(fmaxf(a, b), c);
}

__global__ __launch_bounds__(256, 6) void skel_iter(
    const float* __restrict__ srcA, float* __restrict__ dstA,
    const float* __restrict__ othA, double* __restrict__ partA,
    const float* __restrict__ srcB, float* __restrict__ dstB,
    const float* __restrict__ othB, double* __restrict__ partB,
    int last) {
  const int tid = threadIdx.x;
  const int lane = tid & 63;
  const int wv = tid >> 6;
  const int gy = blockIdx.x * WPB + wv;     // strip row 0..191
  const int chunk = blockIdx.y;             // 0..NCH-1
  const int b = blockIdx.z % B;
  const int chain = blockIdx.z / B;

  const float* __restrict__ vs = (chain ? srcB : srcA) + (size_t)b * VOL;
  float* __restrict__ vd = (chain ? dstB : dstA) + (size_t)b * VOL;
  const float* __restrict__ vo = (chain ? othB : othA) + (size_t)b * VOL;
  double* __restrict__ part = chain ? partB : partA;

  const int z0 = chunk * CZ;                // z0 % 4 == 0 (CZ mult of 4)
  const int c0 = 3 * lane;

  // Row offsets (z-invariant), rows gy-2..gy+2 clamped (dup is min-neutral;
  // out-of-volume M rows masked below).
  int rb[5];
  #pragma unroll
  for (int r = 0; r < 5; ++r) rb[r] = min(max(gy - 2 + r, 0), H - 1) * W + c0;
  const bool ytop = (gy == 0), ybot = (gy == H - 1);
  const bool l0 = (lane == 0), l63 = (lane == 63);

  // Register state: ring indices all compile-time via the mod-4 phase unroll.
  float xa[4][5][3];     // x plane ring: plane q in slot q&3
  float Mprev[3];        // M(z-2), center row (for out)
  float h1[3], h2[3];    // hxy(z-2), hxy(z-3)
  float sp = 0.0f, ss = 0.0f;

  // Prologue: planes z0-2 -> slot 2, z0-1 -> slot 3 (clamped at z0==0).
  {
    const float* ps = vs + (size_t)max(z0 - 2, 0) * HW;
    #pragma unroll
    for (int r = 0; r < 5; ++r) {
      const F3 v = *(const F3*)(ps + rb[r]);
      xa[2][r][0] = v.x; xa[2][r][1] = v.y; xa[2][r][2] = v.z;
    }
    ps = vs + (size_t)max(z0 - 1, 0) * HW;
    #pragma unroll
    for (int r = 0; r < 5; ++r) {
      const F3 v = *(const F3*)(ps + rb[r]);
      xa[3][r][0] = v.x; xa[3][r][1] = v.y; xa[3][r][2] = v.z;
    }
  }

  #pragma unroll 1
  for (int s4 = 0; s4 < STEPS; s4 += 4) {
    #pragma unroll
    for (int p = 0; p < 4; ++p) {
      const int s = s4 + p;
      const int z = z0 - 1 + s;                  // pipeline front
      const int ld = p;                          // slot for plane z+1
      const int sm2 = (p + 1) & 3;               // plane z-2
      const int sm1 = (p + 2) & 3;               // plane z-1 (M center)
      const int sc = (p + 3) & 3;                // plane z

      // Issue next-plane loads early (consumed next step).
      {
        const int zc = min(z + 1, D - 1);
        const float* ps = vs + (size_t)zc * HW;
        #pragma unroll
        for (int r = 0; r < 5; ++r) {
          const F3 v = *(const F3*)(ps + rb[r]);
          xa[ld][r][0] = v.x; xa[ld][r][1] = v.y; xa[ld][r][2] = v.z;
        }
      }

      const int zo = z - 2;
      const bool emit = (s >= 3) && (s <= CZ + 2);

      // Weight row for the fused reduction (last iteration only).
      float w0 = 0.f, w1 = 0.f, w2 = 0.f;
      if (last && emit) {
        const F3 wv3 = *(const F3*)(vo + (size_t)zo * HW + rb[2]);
        w0 = wv3.x; w1 = wv3.y; w2 = wv3.z;
      }

      // ---- M(z-1): 7-pt cross min, rows gy-1..gy+1 (M rows 0..2) ----
      float xl[3], xr[3];
      #pragma unroll
      for (int r = 0; r < 3; ++r) {
        xl[r] = __shfl_up(xa[sm1][r + 1][2], 1, 64);    // col 3l-1
        xr[r] = __shfl_down(xa[sm1][r + 1][0], 1, 64);  // col 3l+3
        if (l0) xl[r] = FLT_MAX;    // x = -1  -> +inf pad (min-neutral)
        if (l63) xr[r] = FLT_MAX;   // x = 192 -> +inf pad
      }
      float Mc[3][3];
      #pragma unroll
      for (int r = 0; r < 3; ++r) {
        #pragma unroll
        for (int c = 0; c < 3; ++c) {
          const float le = (c == 0) ? xl[r] : xa[sm1][r + 1][c - 1];
          const float ri = (c == 2) ? xr[r] : xa[sm1][r + 1][c + 1];
          float v = fminf(xa[sm1][r + 1][c], fminf(le, ri));
          v = fminf(v, fminf(xa[sm1][r][c], xa[sm1][r + 2][c]));      // y+-1
          v = fminf(v, fminf(xa[sm2][r + 1][c], xa[sc][r + 1][c]));   // z+-1
          Mc[r][c] = v;
        }
      }
      // Out-of-volume M rows -> -inf (exact reduce_window -inf-pad for P).
      if (ytop) { Mc[0][0] = Mc[0][1] = Mc[0][2] = -FLT_MAX; }
      if (ybot) { Mc[2][0] = Mc[2][1] = Mc[2][2] = -FLT_MAX; }

      // ---- hxy(z-1): separable 3x3 max — row-max in-register, 2 shfls ----
      float rm[3];
      #pragma unroll
      for (int c = 0; c < 3; ++c) rm[c] = max3(Mc[0][c], Mc[1][c], Mc[2][c]);
      float ml = __shfl_up(rm[2], 1, 64);
      float mr = __shfl_down(rm[0], 1, 64);
      if (l0) ml = -FLT_MAX;
      if (l63) mr = -FLT_MAX;
      float h0c[3];
      h0c[0] = max3(ml, rm[0], rm[1]);
      h0c[1] = max3(rm[0], rm[1], rm[2]);
      h0c[2] = max3(rm[1], rm[2], mr);

      // ---- out(z-2) = relu(x - relu(P - M)) ----
      if (emit) {
        const bool zlo = (zo > 0), zhi = (zo < D - 1);
        float o[3];
        #pragma unroll
        for (int c = 0; c < 3; ++c) {
          float P = h1[c];
          if (zlo) P = fmaxf(P, h2[c]);
          if (zhi) P = fmaxf(P, h0c[c]);
          const float contour = fmaxf(P - Mprev[c], 0.0f);
          o[c] = fmaxf(xa[sm2][2][c] - contour, 0.0f);
        }
        if (last) {
          sp += o[0] * w0 + o[1] * w1 + o[2] * w2;
          ss += o[0] + o[1] + o[2];
        } else {
          *(F3*)(vd + (size_t)zo * HW + rb[2]) = {o[0], o[1], o[2]};
        }
      }

      // Ring advance (static names; compiler renames).
      #pragma unroll
      for (int c = 0; c < 3; ++c) {
        h2[c] = h1[c];
        h1[c] = h0c[c];
        Mprev[c] = Mc[1][c];
      }
    }
  }

  if (last) {
    #pragma unroll
    for (int off = 32; off > 0; off >>= 1) {
      sp += __shfl_down(sp, off, 64);
      ss += __shfl_down(ss, off, 64);
    }
    if (lane == 0) {
      const int lin = (b * NCH + chunk) * H + gy;
      part[2 * lin] = (double)sp;
      part[2 * lin + 1] = (double)ss;
    }
  }
}

__global__ void finalize_kernel(const double* __restrict__ pa,
                                const double* __restrict__ pb,
                                float* __restrict__ out, int npart) {
  __shared__ double red[4][4];
  double s[4] = {0, 0, 0, 0};
  for (int i = threadIdx.x; i < npart; i += 256) {
    s[0] += pa[2 * i];
    s[1] += pa[2 * i + 1];
    s[2] += pb[2 * i];
    s[3] += pb[2 * i + 1];
  }
  #pragma unroll
  for (int off = 32; off > 0; off >>= 1)
    #pragma unroll
    for (int j = 0; j < 4; ++j) s[j] += __shfl_down(s[j], off, 64);
  const int wave = threadIdx.x >> 6, lane = threadIdx.x & 63;
  if (lane == 0)
    for (int j = 0; j < 4; ++j) red[j][wave] = s[j];
  __syncthreads();
  if (threadIdx.x == 0) {
    double t[4];
    for (int j = 0; j < 4; ++j)
      t[j] = red[j][0] + red[j][1] + red[j][2] + red[j][3];
    const double recall = (t[0] + 1e-12) / (t[1] + 1e-12);
    const double accv = (t[2] + 1e-12) / (t[3] + 1e-12);
    const double cldice = 2.0 * recall * accv / (recall + accv);
    out[0] = (float)(1.0 - cldice);
  }
}

extern "C" void kernel_launch(void* const* d_in, const int* in_sizes, int n_in,
                              void* d_out, int out_size, void* d_ws, size_t ws_size,
                              hipStream_t stream) {
  const float* pred = (const float*)d_in[0];
  const float* target = (const float*)d_in[1];
  float* out = (float*)d_out;
  const size_t NT = (size_t)VOL * B;

  const dim3 blk(256, 1, 1);
  const size_t need_merged = 4 * NT * sizeof(float) + 4 * NPART * sizeof(double);

  if (ws_size >= need_merged) {
    float* a0 = (float*)d_ws;
    float* a1 = a0 + NT;
    float* c0 = a1 + NT;
    float* c1 = c0 + NT;
    double* pA = (double*)(c1 + NT);
    double* pB = pA + 2 * NPART;
    const dim3 grd(NGY, NCH, 2 * B);   // 1536 blocks = exactly 6/CU
    skel_iter<<<grd, blk, 0, stream>>>(target, a0, pred, pA, pred, c0, target, pB, 0);
    skel_iter<<<grd, blk, 0, stream>>>(a0, a1, pred, pA, c0, c1, target, pB, 0);
    skel_iter<<<grd, blk, 0, stream>>>(a1, a0, pred, pA, c1, c0, target, pB, 0);
    skel_iter<<<grd, blk, 0, stream>>>(a0, a1, pred, pA, c0, c1, target, pB, 0);
    skel_iter<<<grd, blk, 0, stream>>>(a1, a0, pred, pA, c1, c0, target, pB, 1);
    finalize_kernel<<<1, 256, 0, stream>>>(pA, pB, out, NPART);
  } else {
    float* b0 = (float*)d_ws;
    float* b1 = b0 + NT;
    double* pA = (double*)(b1 + NT);
    double* pB = pA + 2 * NPART;
    const dim3 grd(NGY, NCH, B);       // chain = 0 only
    skel_iter<<<grd, blk, 0, stream>>>(target, b0, pred, pA, nullptr, nullptr, nullptr, nullptr, 0);
    skel_iter<<<grd, blk, 0, stream>>>(b0, b1, pred, pA, nullptr, nullptr, nullptr, nullptr, 0);
    skel_iter<<<grd, blk, 0, stream>>>(b1, b0, pred, pA, nullptr, nullptr, nullptr, nullptr, 0);
    skel_iter<<<grd, blk, 0, stream>>>(b0, b1, pred, pA, nullptr, nullptr, nullptr, nullptr, 0);
    skel_iter<<<grd, blk, 0, stream>>>(b1, b0, pred, pA, nullptr, nullptr, nullptr, nullptr, 1);
    skel_iter<<<grd, blk, 0, stream>>>(pred, b0, target, pB, nullptr, nullptr, nullptr, nullptr, 0);
    skel_iter<<<grd, blk, 0, stream>>>(b0, b1, target, pB, nullptr, nullptr, nullptr, nullptr, 0);
    skel_iter<<<grd, blk, 0, stream>>>(b1, b0, target, pB, nullptr, nullptr, nullptr, nullptr, 0);
    skel_iter<<<grd, blk, 0, stream>>>(b0, b1, target, pB, nullptr, nullptr, nullptr, nullptr, 0);
    skel_iter<<<grd, blk, 0, stream>>>(b1, b0, target, pB, nullptr, nullptr, nullptr, nullptr, 1);
    finalize_kernel<<<1, 256, 0, stream>>>(pA, pB, out, NPART);
  }
}

// Round 3
// 374.419 us; speedup vs baseline: 2.8979x; 2.8979x over previous
//
#include <hip/hip_runtime.h>
#include <cfloat>

// ClDiceLoss (B=2, C=1, 192^3) fp32 — register-streaming soft-skeletonize.
//
// Round-10. Round-9 (CZ=24, 6 waves/SIMD) exploded FETCH 120->463 MB: 32
// concurrent plane-windows + round-robin XCD placement broke L2 halo
// absorption -> HBM-traffic-bound at 218us. Revert to CZ=48 (16 windows,
// fetch was 1.06x ideal) and attack round-8's real limiter (MLP/latency):
//   (a) XCD swizzle (bijective, 768%8==0): each XCD owns 2 complete
//       (chunk,b,chain) windows with ALL 48 gy-blocks -> y-halo re-reads
//       (each row read by 5 waves) are local-L2 hits (~1.8MB/XCD window).
//   (b) ring-5 plane buffer, loads issued 2 steps ahead of consumption ->
//       2x bytes in flight per wave; load latency off the critical path.
//   (c) keep dwordx3 loads/stores + separable 3x3 max (8 bpermutes/step).
// Decomposition: W = 192 = 64 lanes x 3 cols -> one wave spans full x;
// wave owns y-row gy; rows gy-2..gy+2 per plane (halo rows re-read from
// global = L2 hits). M: x+-1 via shfl, y+-1 in-register, z+-1 ring.
// P: separable 3x3 max + 3-deep hxy shift (h2,h1,h0). out(z-2) trails.
// Boundaries: x edge == wave edge -> cndmask pads; y edge -> -FLT_MAX M
// rows; z edge -> zlo/zhi guards; clamped dup loads are min-neutral.
// No __shared__, no __syncthreads in skel_iter.

constexpr int D = 192, H = 192, W = 192, B = 2;
constexpr int HW = H * W;
constexpr int VOL = D * HW;
constexpr int CZ = 48;              // z-chunk (divides D)
constexpr int NCH = D / CZ;         // 4 chunks
constexpr int WPB = 4;              // waves (y-strips) per block
constexpr int NGY = H / WPB;        // 48
constexpr int STEPS = 55;           // ring-5 phases; emit window s in [3,50]
constexpr int NPART = B * NCH * H;  // 1536 per chain

struct F3 { float x, y, z; };       // 12B -> global_load_dwordx3

__device__ __forceinline__ float min3f(float a, float b, float c) {
  return fminf(fminf(a, b), c);
}
__device__ __forceinline__ float max3f(float a, float b, float c) {
  return fmaxf(fmaxf(a, b), c);
}

__global__ __launch_bounds__(256, 3) void skel_iter(
    const float* __restrict__ srcA, float* __restrict__ dstA,
    const float* __restrict__ othA, double* __restrict__ partA,
    const float* __restrict__ srcB, float* __restrict__ dstB,
    const float* __restrict__ othB, double* __restrict__ partB,
    int last) {
  const int tid = threadIdx.x;
  const int lane = tid & 63;
  const int wv = tid >> 6;

  // ---- XCD-locality swizzle (bijective: nwg % 8 == 0) ----
  // HW round-robins linear block id across 8 XCDs; remap so each XCD gets
  // contiguous work ids = whole (chunk,b,chain) windows with all gy strips.
  const int nwg = gridDim.x * gridDim.y * gridDim.z;
  int wid = blockIdx.x + gridDim.x * (blockIdx.y + gridDim.y * blockIdx.z);
  wid = (wid & 7) * (nwg >> 3) + (wid >> 3);
  const int gyg = wid % NGY;
  const int combo = wid / NGY;
  const int chunk = combo % NCH;
  const int bz = combo / NCH;
  const int b = bz % B;
  const int chain = bz / B;

  const int gy = gyg * WPB + wv;            // strip row 0..191

  const float* __restrict__ vs = (chain ? srcB : srcA) + (size_t)b * VOL;
  float* __restrict__ vd = (chain ? dstB : dstA) + (size_t)b * VOL;
  const float* __restrict__ vo = (chain ? othB : othA) + (size_t)b * VOL;
  double* __restrict__ part = chain ? partB : partA;

  const int z0 = chunk * CZ;
  const int c0 = 3 * lane;

  // Row offsets (z-invariant), rows gy-2..gy+2 clamped (dup is min-neutral;
  // out-of-volume M rows masked below).
  int rb[5];
  #pragma unroll
  for (int r = 0; r < 5; ++r) rb[r] = min(max(gy - 2 + r, 0), H - 1) * W + c0;
  const bool ytop = (gy == 0), ybot = (gy == H - 1);
  const bool l0 = (lane == 0), l63 = (lane == 63);

  // Register state. Ring slot of plane q is (q - z0) mod 5; all slot
  // indices below are compile-time via the 5-phase unroll.
  float xa[5][5][3];     // x plane ring
  float Mprev[3];        // M(z-2), center row (for out)
  float h1[3], h2[3];    // hxy(z-2), hxy(z-3)
  float sp = 0.0f, ss = 0.0f;

  // Prologue: z0-2 -> slot 3, z0-1 -> slot 4 (consumed at s=0);
  // z0 -> slot 0 (consumed at s=1; ~1 step of slack).
  {
    const float* ps = vs + (size_t)max(z0 - 2, 0) * HW;
    #pragma unroll
    for (int r = 0; r < 5; ++r) {
      const F3 v = *(const F3*)(ps + rb[r]);
      xa[3][r][0] = v.x; xa[3][r][1] = v.y; xa[3][r][2] = v.z;
    }
    ps = vs + (size_t)max(z0 - 1, 0) * HW;
    #pragma unroll
    for (int r = 0; r < 5; ++r) {
      const F3 v = *(const F3*)(ps + rb[r]);
      xa[4][r][0] = v.x; xa[4][r][1] = v.y; xa[4][r][2] = v.z;
    }
    ps = vs + (size_t)z0 * HW;
    #pragma unroll
    for (int r = 0; r < 5; ++r) {
      const F3 v = *(const F3*)(ps + rb[r]);
      xa[0][r][0] = v.x; xa[0][r][1] = v.y; xa[0][r][2] = v.z;
    }
  }

  #pragma unroll 1
  for (int s5 = 0; s5 < STEPS; s5 += 5) {
    #pragma unroll
    for (int p = 0; p < 5; ++p) {
      const int s = s5 + p;
      const int z = z0 - 1 + s;                 // pipeline front
      const int LD  = (p + 1) % 5;              // plane z+2 (load target)
      const int SM2 = (p + 2) % 5;              // plane z-2
      const int SM1 = (p + 3) % 5;              // plane z-1 (M center)
      const int SC  = (p + 4) % 5;              // plane z

      // Issue plane z+2 (consumed 2 steps later -> latency decoupled).
      {
        const int zc = min(z + 2, D - 1);
        const float* ps = vs + (size_t)zc * HW;
        #pragma unroll
        for (int r = 0; r < 5; ++r) {
          const F3 v = *(const F3*)(ps + rb[r]);
          xa[LD][r][0] = v.x; xa[LD][r][1] = v.y; xa[LD][r][2] = v.z;
        }
      }

      const int zo = z - 2;
      const bool emit = (s >= 3) && (s <= CZ + 2);

      // Weight row for the fused reduction (last iteration only).
      float w0 = 0.f, w1 = 0.f, w2 = 0.f;
      if (last && emit) {
        const F3 wv3 = *(const F3*)(vo + (size_t)zo * HW + rb[2]);
        w0 = wv3.x; w1 = wv3.y; w2 = wv3.z;
      }

      // ---- M(z-1): 7-pt cross min, rows gy-1..gy+1 (M rows 0..2) ----
      float xl[3], xr[3];
      #pragma unroll
      for (int r = 0; r < 3; ++r) {
        xl[r] = __shfl_up(xa[SM1][r + 1][2], 1, 64);    // col 3l-1
        xr[r] = __shfl_down(xa[SM1][r + 1][0], 1, 64);  // col 3l+3
        if (l0) xl[r] = FLT_MAX;    // x = -1  -> +inf pad (min-neutral)
        if (l63) xr[r] = FLT_MAX;   // x = 192 -> +inf pad
      }
      float Mc[3][3];
      #pragma unroll
      for (int r = 0; r < 3; ++r) {
        #pragma unroll
        for (int c = 0; c < 3; ++c) {
          const float le = (c == 0) ? xl[r] : xa[SM1][r + 1][c - 1];
          const float ri = (c == 2) ? xr[r] : xa[SM1][r + 1][c + 1];
          float v = min3f(xa[SM1][r + 1][c], le, ri);
          v = min3f(v, xa[SM1][r][c], xa[SM1][r + 2][c]);      // y+-1
          v = min3f(v, xa[SM2][r + 1][c], xa[SC][r + 1][c]);   // z+-1
          Mc[r][c] = v;
        }
      }
      // Out-of-volume M rows -> -inf (exact reduce_window -inf-pad for P).
      if (ytop) { Mc[0][0] = Mc[0][1] = Mc[0][2] = -FLT_MAX; }
      if (ybot) { Mc[2][0] = Mc[2][1] = Mc[2][2] = -FLT_MAX; }

      // ---- hxy(z-1): separable 3x3 max — row-max, then 2 shfls ----
      float rm[3];
      #pragma unroll
      for (int c = 0; c < 3; ++c) rm[c] = max3f(Mc[0][c], Mc[1][c], Mc[2][c]);
      float ml = __shfl_up(rm[2], 1, 64);
      float mr = __shfl_down(rm[0], 1, 64);
      if (l0) ml = -FLT_MAX;
      if (l63) mr = -FLT_MAX;
      float h0c[3];
      h0c[0] = max3f(ml, rm[0], rm[1]);
      h0c[1] = max3f(rm[0], rm[1], rm[2]);
      h0c[2] = max3f(rm[1], rm[2], mr);

      // ---- out(z-2) = relu(x - relu(P - M)) ----
      if (emit) {
        const bool zlo = (zo > 0), zhi = (zo < D - 1);
        float o[3];
        #pragma unroll
        for (int c = 0; c < 3; ++c) {
          float P = h1[c];
          if (zlo) P = fmaxf(P, h2[c]);
          if (zhi) P = fmaxf(P, h0c[c]);
          const float contour = fmaxf(P - Mprev[c], 0.0f);
          o[c] = fmaxf(xa[SM2][2][c] - contour, 0.0f);
        }
        if (last) {
          sp += o[0] * w0 + o[1] * w1 + o[2] * w2;
          ss += o[0] + o[1] + o[2];
        } else {
          *(F3*)(vd + (size_t)zo * HW + rb[2]) = {o[0], o[1], o[2]};
        }
      }

      // Ring advance (static names; compiler renames across phases).
      #pragma unroll
      for (int c = 0; c < 3; ++c) {
        h2[c] = h1[c];
        h1[c] = h0c[c];
        Mprev[c] = Mc[1][c];
      }
    }
  }

  if (last) {
    #pragma unroll
    for (int off = 32; off > 0; off >>= 1) {
      sp += __shfl_down(sp, off, 64);
      ss += __shfl_down(ss, off, 64);
    }
    if (lane == 0) {
      const int lin = (b * NCH + chunk) * H + gy;
      part[2 * lin] = (double)sp;
      part[2 * lin + 1] = (double)ss;
    }
  }
}

__global__ void finalize_kernel(const double* __restrict__ pa,
                                const double* __restrict__ pb,
                                float* __restrict__ out, int npart) {
  __shared__ double red[4][4];
  double s[4] = {0, 0, 0, 0};
  for (int i = threadIdx.x; i < npart; i += 256) {
    s[0] += pa[2 * i];
    s[1] += pa[2 * i + 1];
    s[2] += pb[2 * i];
    s[3] += pb[2 * i + 1];
  }
  #pragma unroll
  for (int off = 32; off > 0; off >>= 1)
    #pragma unroll
    for (int j = 0; j < 4; ++j) s[j] += __shfl_down(s[j], off, 64);
  const int wave = threadIdx.x >> 6, lane = threadIdx.x & 63;
  if (lane == 0)
    for (int j = 0; j < 4; ++j) red[j][wave] = s[j];
  __syncthreads();
  if (threadIdx.x == 0) {
    double t[4];
    for (int j = 0; j < 4; ++j)
      t[j] = red[j][0] + red[j][1] + red[j][2] + red[j][3];
    const double recall = (t[0] + 1e-12) / (t[1] + 1e-12);
    const double accv = (t[2] + 1e-12) / (t[3] + 1e-12);
    const double cldice = 2.0 * recall * accv / (recall + accv);
    out[0] = (float)(1.0 - cldice);
  }
}

extern "C" void kernel_launch(void* const* d_in, const int* in_sizes, int n_in,
                              void* d_out, int out_size, void* d_ws, size_t ws_size,
                              hipStream_t stream) {
  const float* pred = (const float*)d_in[0];
  const float* target = (const float*)d_in[1];
  float* out = (float*)d_out;
  const size_t NT = (size_t)VOL * B;

  const dim3 blk(256, 1, 1);
  const size_t need_merged = 4 * NT * sizeof(float) + 4 * NPART * sizeof(double);

  if (ws_size >= need_merged) {
    float* a0 = (float*)d_ws;
    float* a1 = a0 + NT;
    float* c0 = a1 + NT;
    float* c1 = c0 + NT;
    double* pA = (double*)(c1 + NT);
    double* pB = pA + 2 * NPART;
    const dim3 grd(NGY, NCH, 2 * B);   // 768 blocks = exactly 3/CU
    skel_iter<<<grd, blk, 0, stream>>>(target, a0, pred, pA, pred, c0, target, pB, 0);
    skel_iter<<<grd, blk, 0, stream>>>(a0, a1, pred, pA, c0, c1, target, pB, 0);
    skel_iter<<<grd, blk, 0, stream>>>(a1, a0, pred, pA, c1, c0, target, pB, 0);
    skel_iter<<<grd, blk, 0, stream>>>(a0, a1, pred, pA, c0, c1, target, pB, 0);
    skel_iter<<<grd, blk, 0, stream>>>(a1, a0, pred, pA, c1, c0, target, pB, 1);
    finalize_kernel<<<1, 256, 0, stream>>>(pA, pB, out, NPART);
  } else {
    float* b0 = (float*)d_ws;
    float* b1 = b0 + NT;
    double* pA = (double*)(b1 + NT);
    double* pB = pA + 2 * NPART;
    const dim3 grd(NGY, NCH, B);       // chain = 0 only, 384 blocks
    skel_iter<<<grd, blk, 0, stream>>>(target, b0, pred, pA, nullptr, nullptr, nullptr, nullptr, 0);
    skel_iter<<<grd, blk, 0, stream>>>(b0, b1, pred, pA, nullptr, nullptr, nullptr, nullptr, 0);
    skel_iter<<<grd, blk, 0, stream>>>(b1, b0, pred, pA, nullptr, nullptr, nullptr, nullptr, 0);
    skel_iter<<<grd, blk, 0, stream>>>(b0, b1, pred, pA, nullptr, nullptr, nullptr, nullptr, 0);
    skel_iter<<<grd, blk, 0, stream>>>(b1, b0, pred, pA, nullptr, nullptr, nullptr, nullptr, 1);
    skel_iter<<<grd, blk, 0, stream>>>(pred, b0, target, pB, nullptr, nullptr, nullptr, nullptr, 0);
    skel_iter<<<grd, blk, 0, stream>>>(b0, b1, target, pB, nullptr, nullptr, nullptr, nullptr, 0);
    skel_iter<<<grd, blk, 0, stream>>>(b1, b0, target, pB, nullptr, nullptr, nullptr, nullptr, 0);
    skel_iter<<<grd, blk, 0, stream>>>(b0, b1, target, pB, nullptr, nullptr, nullptr, nullptr, 0);
    skel_iter<<<grd, blk, 0, stream>>>(b1, b0, target, pB, nullptr, nullptr, nullptr, nullptr, 1);
    finalize_kernel<<<1, 256, 0, stream>>>(pA, pB, out, NPART);
  }
}

// Round 4
// 367.622 us; speedup vs baseline: 2.9515x; 1.0185x over previous
//
#include <hip/hip_runtime.h>
#include <cfloat>

// ClDiceLoss (B=2, C=1, 192^3) fp32 — register-streaming soft-skeletonize.
//
// Round-11. Round-10 diagnosis: VGPR_Count=60 proves the compiler SANK the
// 2-ahead prefetch loads to their use point (ring-5 live = 75 floats > 60),
// collapsing prefetch distance to zero -> every step pays ~1200cy of load
// latency serially (83us with VALU 26% / HBM 27% / occ 28% all idle).
// Fix: __builtin_amdgcn_sched_barrier(0) right after each phase's load-issue
// block — scheduling regions stop the sink; waitcnt pass then emits counted
// vmcnt(N>0) two phases downstream. launch_bounds(256,4) caps VGPR at 128
// (occupancy cliff: waves/CU halves at 64/128/256; grid is 3 blocks/CU).
// Verification tell: VGPR must rise to ~95-128. If it stays ~60, theory is
// falsified and the next ablation target is the shfl chain.
//
// Kept from round-10: CZ=48 (16 windows, fetch 64MB = L2-absorbed halos),
// bijective XCD swizzle (each XCD owns 2 whole windows, all 48 gy-strips),
// dwordx3 loads/stores, separable 3x3 max (8 bpermutes/step).
// Decomposition: W = 192 = 64 lanes x 3 cols -> one wave spans full x;
// wave owns y-row gy; rows gy-2..gy+2 per plane; ring-5 z-stream.
// Boundaries: x edge == wave edge -> cndmask pads; y edge -> -FLT_MAX M
// rows; z edge -> zlo/zhi guards; clamped dup loads are min-neutral.
// No __shared__, no __syncthreads in skel_iter.

constexpr int D = 192, H = 192, W = 192, B = 2;
constexpr int HW = H * W;
constexpr int VOL = D * HW;
constexpr int CZ = 48;              // z-chunk (divides D)
constexpr int NCH = D / CZ;         // 4 chunks
constexpr int WPB = 4;              // waves (y-strips) per block
constexpr int NGY = H / WPB;        // 48
constexpr int STEPS = 55;           // ring-5 phases; emit window s in [3,50]
constexpr int NPART = B * NCH * H;  // 1536 per chain

struct F3 { float x, y, z; };       // 12B -> global_load_dwordx3

__device__ __forceinline__ float min3f(float a, float b, float c) {
  return fminf(fminf(a, b), c);
}
__device__ __forceinline__ float max3f(float a, float b, float c) {
  return fmaxf(fmaxf(a, b), c);
}

__global__ __launch_bounds__(256, 4) void skel_iter(
    const float* __restrict__ srcA, float* __restrict__ dstA,
    const float* __restrict__ othA, double* __restrict__ partA,
    const float* __restrict__ srcB, float* __restrict__ dstB,
    const float* __restrict__ othB, double* __restrict__ partB,
    int last) {
  const int tid = threadIdx.x;
  const int lane = tid & 63;
  const int wv = tid >> 6;

  // ---- XCD-locality swizzle (bijective: nwg % 8 == 0) ----
  const int nwg = gridDim.x * gridDim.y * gridDim.z;
  int wid = blockIdx.x + gridDim.x * (blockIdx.y + gridDim.y * blockIdx.z);
  wid = (wid & 7) * (nwg >> 3) + (wid >> 3);
  const int gyg = wid % NGY;
  const int combo = wid / NGY;
  const int chunk = combo % NCH;
  const int bz = combo / NCH;
  const int b = bz % B;
  const int chain = bz / B;

  const int gy = gyg * WPB + wv;            // strip row 0..191

  const float* __restrict__ vs = (chain ? srcB : srcA) + (size_t)b * VOL;
  float* __restrict__ vd = (chain ? dstB : dstA) + (size_t)b * VOL;
  const float* __restrict__ vo = (chain ? othB : othA) + (size_t)b * VOL;
  double* __restrict__ part = chain ? partB : partA;

  const int z0 = chunk * CZ;
  const int c0 = 3 * lane;

  // Row offsets (z-invariant), rows gy-2..gy+2 clamped (dup is min-neutral;
  // out-of-volume M rows masked below).
  int rb[5];
  #pragma unroll
  for (int r = 0; r < 5; ++r) rb[r] = min(max(gy - 2 + r, 0), H - 1) * W + c0;
  const bool ytop = (gy == 0), ybot = (gy == H - 1);
  const bool l0 = (lane == 0), l63 = (lane == 63);

  // Register state. Ring slot of plane q is (q - z0) mod 5; all slot
  // indices below are compile-time via the 5-phase unroll.
  float xa[5][5][3];     // x plane ring (forced live by sched_barriers)
  float Mprev[3];        // M(z-2), center row (for out)
  float h1[3], h2[3];    // hxy(z-2), hxy(z-3)
  float sp = 0.0f, ss = 0.0f;

  // Prologue: z0-2 -> slot 3, z0-1 -> slot 4, z0 -> slot 0.
  {
    const float* ps = vs + (size_t)max(z0 - 2, 0) * HW;
    #pragma unroll
    for (int r = 0; r < 5; ++r) {
      const F3 v = *(const F3*)(ps + rb[r]);
      xa[3][r][0] = v.x; xa[3][r][1] = v.y; xa[3][r][2] = v.z;
    }
    ps = vs + (size_t)max(z0 - 1, 0) * HW;
    #pragma unroll
    for (int r = 0; r < 5; ++r) {
      const F3 v = *(const F3*)(ps + rb[r]);
      xa[4][r][0] = v.x; xa[4][r][1] = v.y; xa[4][r][2] = v.z;
    }
    ps = vs + (size_t)z0 * HW;
    #pragma unroll
    for (int r = 0; r < 5; ++r) {
      const F3 v = *(const F3*)(ps + rb[r]);
      xa[0][r][0] = v.x; xa[0][r][1] = v.y; xa[0][r][2] = v.z;
    }
  }

  #pragma unroll 1
  for (int s5 = 0; s5 < STEPS; s5 += 5) {
    #pragma unroll
    for (int p = 0; p < 5; ++p) {
      const int s = s5 + p;
      const int z = z0 - 1 + s;                 // pipeline front
      const int LD  = (p + 1) % 5;              // plane z+2 (load target)
      const int SM2 = (p + 2) % 5;              // plane z-2
      const int SM1 = (p + 3) % 5;              // plane z-1 (M center)
      const int SC  = (p + 4) % 5;              // plane z

      // Issue plane z+2 (consumed 2 phases later).
      {
        const int zc = min(z + 2, D - 1);
        const float* ps = vs + (size_t)zc * HW;
        #pragma unroll
        for (int r = 0; r < 5; ++r) {
          const F3 v = *(const F3*)(ps + rb[r]);
          xa[LD][r][0] = v.x; xa[LD][r][1] = v.y; xa[LD][r][2] = v.z;
        }
      }
      // Weight row for the fused reduction (last iteration only) — issue
      // with the plane loads so it shares the same pin.
      const int zo = z - 2;
      const bool emit = (s >= 3) && (s <= CZ + 2);
      float w0 = 0.f, w1 = 0.f, w2 = 0.f;
      if (last && emit) {
        const F3 wv3 = *(const F3*)(vo + (size_t)zo * HW + rb[2]);
        w0 = wv3.x; w1 = wv3.y; w2 = wv3.z;
      }
      // Pin: loads above may not sink past this point (prevents the
      // register-pressure scheduler from collapsing the prefetch ring).
      __builtin_amdgcn_sched_barrier(0);

      // ---- M(z-1): 7-pt cross min, rows gy-1..gy+1 (M rows 0..2) ----
      float xl[3], xr[3];
      #pragma unroll
      for (int r = 0; r < 3; ++r) {
        xl[r] = __shfl_up(xa[SM1][r + 1][2], 1, 64);    // col 3l-1
        xr[r] = __shfl_down(xa[SM1][r + 1][0], 1, 64);  // col 3l+3
        if (l0) xl[r] = FLT_MAX;    // x = -1  -> +inf pad (min-neutral)
        if (l63) xr[r] = FLT_MAX;   // x = 192 -> +inf pad
      }
      float Mc[3][3];
      #pragma unroll
      for (int r = 0; r < 3; ++r) {
        #pragma unroll
        for (int c = 0; c < 3; ++c) {
          const float le = (c == 0) ? xl[r] : xa[SM1][r + 1][c - 1];
          const float ri = (c == 2) ? xr[r] : xa[SM1][r + 1][c + 1];
          float v = min3f(xa[SM1][r + 1][c], le, ri);
          v = min3f(v, xa[SM1][r][c], xa[SM1][r + 2][c]);      // y+-1
          v = min3f(v, xa[SM2][r + 1][c], xa[SC][r + 1][c]);   // z+-1
          Mc[r][c] = v;
        }
      }
      // Out-of-volume M rows -> -inf (exact reduce_window -inf-pad for P).
      if (ytop) { Mc[0][0] = Mc[0][1] = Mc[0][2] = -FLT_MAX; }
      if (ybot) { Mc[2][0] = Mc[2][1] = Mc[2][2] = -FLT_MAX; }

      // ---- hxy(z-1): separable 3x3 max — row-max, then 2 shfls ----
      float rm[3];
      #pragma unroll
      for (int c = 0; c < 3; ++c) rm[c] = max3f(Mc[0][c], Mc[1][c], Mc[2][c]);
      float ml = __shfl_up(rm[2], 1, 64);
      float mr = __shfl_down(rm[0], 1, 64);
      if (l0) ml = -FLT_MAX;
      if (l63) mr = -FLT_MAX;
      float h0c[3];
      h0c[0] = max3f(ml, rm[0], rm[1]);
      h0c[1] = max3f(rm[0], rm[1], rm[2]);
      h0c[2] = max3f(rm[1], rm[2], mr);

      // ---- out(z-2) = relu(x - relu(P - M)) ----
      if (emit) {
        const bool zlo = (zo > 0), zhi = (zo < D - 1);
        float o[3];
        #pragma unroll
        for (int c = 0; c < 3; ++c) {
          float P = h1[c];
          if (zlo) P = fmaxf(P, h2[c]);
          if (zhi) P = fmaxf(P, h0c[c]);
          const float contour = fmaxf(P - Mprev[c], 0.0f);
          o[c] = fmaxf(xa[SM2][2][c] - contour, 0.0f);
        }
        if (last) {
          sp += o[0] * w0 + o[1] * w1 + o[2] * w2;
          ss += o[0] + o[1] + o[2];
        } else {
          *(F3*)(vd + (size_t)zo * HW + rb[2]) = {o[0], o[1], o[2]};
        }
      }

      // Ring advance (static names; compiler renames across phases).
      #pragma unroll
      for (int c = 0; c < 3; ++c) {
        h2[c] = h1[c];
        h1[c] = h0c[c];
        Mprev[c] = Mc[1][c];
      }
    }
  }

  if (last) {
    #pragma unroll
    for (int off = 32; off > 0; off >>= 1) {
      sp += __shfl_down(sp, off, 64);
      ss += __shfl_down(ss, off, 64);
    }
    if (lane == 0) {
      const int lin = (b * NCH + chunk) * H + gy;
      part[2 * lin] = (double)sp;
      part[2 * lin + 1] = (double)ss;
    }
  }
}

__global__ void finalize_kernel(const double* __restrict__ pa,
                                const double* __restrict__ pb,
                                float* __restrict__ out, int npart) {
  __shared__ double red[4][4];
  double s[4] = {0, 0, 0, 0};
  for (int i = threadIdx.x; i < npart; i += 256) {
    s[0] += pa[2 * i];
    s[1] += pa[2 * i + 1];
    s[2] += pb[2 * i];
    s[3] += pb[2 * i + 1];
  }
  #pragma unroll
  for (int off = 32; off > 0; off >>= 1)
    #pragma unroll
    for (int j = 0; j < 4; ++j) s[j] += __shfl_down(s[j], off, 64);
  const int wave = threadIdx.x >> 6, lane = threadIdx.x & 63;
  if (lane == 0)
    for (int j = 0; j < 4; ++j) red[j][wave] = s[j];
  __syncthreads();
  if (threadIdx.x == 0) {
    double t[4];
    for (int j = 0; j < 4; ++j)
      t[j] = red[j][0] + red[j][1] + red[j][2] + red[j][3];
    const double recall = (t[0] + 1e-12) / (t[1] + 1e-12);
    const double accv = (t[2] + 1e-12) / (t[3] + 1e-12);
    const double cldice = 2.0 * recall * accv / (recall + accv);
    out[0] = (float)(1.0 - cldice);
  }
}

extern "C" void kernel_launch(void* const* d_in, const int* in_sizes, int n_in,
                              void* d_out, int out_size, void* d_ws, size_t ws_size,
                              hipStream_t stream) {
  const float* pred = (const float*)d_in[0];
  const float* target = (const float*)d_in[1];
  float* out = (float*)d_out;
  const size_t NT = (size_t)VOL * B;

  const dim3 blk(256, 1, 1);
  const size_t need_merged = 4 * NT * sizeof(float) + 4 * NPART * sizeof(double);

  if (ws_size >= need_merged) {
    float* a0 = (float*)d_ws;
    float* a1 = a0 + NT;
    float* c0 = a1 + NT;
    float* c1 = c0 + NT;
    double* pA = (double*)(c1 + NT);
    double* pB = pA + 2 * NPART;
    const dim3 grd(NGY, NCH, 2 * B);   // 768 blocks = exactly 3/CU
    skel_iter<<<grd, blk, 0, stream>>>(target, a0, pred, pA, pred, c0, target, pB, 0);
    skel_iter<<<grd, blk, 0, stream>>>(a0, a1, pred, pA, c0, c1, target, pB, 0);
    skel_iter<<<grd, blk, 0, stream>>>(a1, a0, pred, pA, c1, c0, target, pB, 0);
    skel_iter<<<grd, blk, 0, stream>>>(a0, a1, pred, pA, c0, c1, target, pB, 0);
    skel_iter<<<grd, blk, 0, stream>>>(a1, a0, pred, pA, c1, c0, target, pB, 1);
    finalize_kernel<<<1, 256, 0, stream>>>(pA, pB, out, NPART);
  } else {
    float* b0 = (float*)d_ws;
    float* b1 = b0 + NT;
    double* pA = (double*)(b1 + NT);
    double* pB = pA + 2 * NPART;
    const dim3 grd(NGY, NCH, B);       // chain = 0 only, 384 blocks
    skel_iter<<<grd, blk, 0, stream>>>(target, b0, pred, pA, nullptr, nullptr, nullptr, nullptr, 0);
    skel_iter<<<grd, blk, 0, stream>>>(b0, b1, pred, pA, nullptr, nullptr, nullptr, nullptr, 0);
    skel_iter<<<grd, blk, 0, stream>>>(b1, b0, pred, pA, nullptr, nullptr, nullptr, nullptr, 0);
    skel_iter<<<grd, blk, 0, stream>>>(b0, b1, pred, pA, nullptr, nullptr, nullptr, nullptr, 0);
    skel_iter<<<grd, blk, 0, stream>>>(b1, b0, pred, pA, nullptr, nullptr, nullptr, nullptr, 1);
    skel_iter<<<grd, blk, 0, stream>>>(pred, b0, target, pB, nullptr, nullptr, nullptr, nullptr, 0);
    skel_iter<<<grd, blk, 0, stream>>>(b0, b1, target, pB, nullptr, nullptr, nullptr, nullptr, 0);
    skel_iter<<<grd, blk, 0, stream>>>(b1, b0, target, pB, nullptr, nullptr, nullptr, nullptr, 0);
    skel_iter<<<grd, blk, 0, stream>>>(b0, b1, target, pB, nullptr, nullptr, nullptr, nullptr, 0);
    skel_iter<<<grd, blk, 0, stream>>>(b1, b0, target, pB, nullptr, nullptr, nullptr, nullptr, 1);
    finalize_kernel<<<1, 256, 0, stream>>>(pA, pB, out, NPART);
  }
}